// Round 9
// baseline (2282.700 us; speedup 1.0000x reference)
//
#include <hip/hip_runtime.h>

#define B_ROWS 8192
#define UNITS 512
#define NITER 25
#define INSZ 176
#define KPAD 128
#define GRAD_COLS 101

typedef __attribute__((ext_vector_type(8))) short short8;
typedef __attribute__((ext_vector_type(4))) float f32x4;
typedef __attribute__((ext_vector_type(8))) _Float16 half8;

__device__ __forceinline__ unsigned short f2h_bits(float f) {
  _Float16 h = (_Float16)f;
  return __builtin_bit_cast(unsigned short, h);
}
__device__ __forceinline__ float h2f_bits(unsigned short b) {
  return (float)__builtin_bit_cast(_Float16, b);
}
__device__ __forceinline__ float fast_tanh(float x) {
  float e = __expf(2.0f * x);
  return 1.0f - 2.0f / (e + 1.0f);
}

typedef __attribute__((address_space(3))) unsigned int lds_u32;
typedef __attribute__((address_space(1))) const unsigned int glb_u32;
__device__ __forceinline__ void gload16(const void* g, void* l) {
  __builtin_amdgcn_global_load_lds((glb_u32*)g, (lds_u32*)l, 16, 0, 0);
}

__device__ __forceinline__ f32x4 mf(short8 a, short8 b, f32x4 c) {
  return __builtin_amdgcn_mfma_f32_16x16x32_f16(
      __builtin_bit_cast(half8, a), __builtin_bit_cast(half8, b), c, 0, 0, 0);
}

struct GArgs {
  const unsigned short *A;            // activations, fp16 plane, M x K
  const unsigned short *B;            // weights, fp16 plane, N x K (n-major)
  int K;
  const float* bias;
  const unsigned short *Hh;           // fwd activations for EPI1
  unsigned short *Oh;                 // output plane (fp16)
  float* Og;                          // grad output (EPI2)
  int iter;
};

// ---------------------------------------------------------------------------
// Weight prep: fp16 planes, n-major layouts, zero-padded.
// ---------------------------------------------------------------------------
__global__ __launch_bounds__(256)
void prep_kernel(const float* __restrict__ W0, const float* __restrict__ W1,
                 const float* __restrict__ W2, const float* __restrict__ W3,
                 unsigned short* TW0, unsigned short* TW1,
                 unsigned short* TW2, unsigned short* TW3,
                 unsigned short* CW0, unsigned short* CW1,
                 unsigned short* CW2, unsigned short* CW3)
{
  int id = blockIdx.x * 256 + threadIdx.x;
  if (id < 512 * KPAD) {
    int n = id >> 7, k = id & (KPAD - 1);
    TW0[id] = f2h_bits((k < 101) ? W0[(size_t)k * 512 + n] : 0.0f);
    int n2 = id >> 9, k2 = id & 511;
    CW0[id] = f2h_bits((n2 < 101) ? W0[(size_t)n2 * 512 + k2] : 0.0f);
  }
  {
    int n = id >> 9, k = id & 511;
    TW1[id] = f2h_bits(W1[(size_t)k * 512 + n]);
    TW2[id] = f2h_bits(W2[(size_t)k * 512 + n]);
    TW3[id] = f2h_bits(W3[(size_t)k * 512 + n]);
    CW1[id] = f2h_bits(W1[id]);
    CW2[id] = f2h_bits(W2[id]);
    CW3[id] = f2h_bits(W3[id]);
  }
}

// ---------------------------------------------------------------------------
// Initial build D_0 (8192 x 128, fp16), zero-padded cols 101..127
// ---------------------------------------------------------------------------
__global__ __launch_bounds__(256)
void build_d_kernel(const float* __restrict__ x, unsigned short* __restrict__ D)
{
  int id = blockIdx.x * 256 + threadIdx.x;     // [0, 8192*128)
  int b = id >> 7, c = id & 127;
  float val;
  if (c < 25)             val = x[(size_t)b * INSZ + c];
  else if (c < 100)       val = x[(size_t)b * INSZ + 26 + (c - 25)];
  else                    val = 0.0f;          // c==100 -> iter 0 == 0.0f
  D[id] = f2h_bits(val);
}

// ---------------------------------------------------------------------------
// GEMM body: C[M x N] = A[M x K] @ B(n-major)[N x K], fp16 single product.
// 256x128 tile, BK=64, 8 waves (4m x 2n, 64x64 each), 512 threads.
// m201-style 8-phase schedule (4 phases per K-tile), 3-buffer LDS ring
// (3 x 48KB = 144KB), 2-deep prefetch, counted vmcnt(6) at tile boundary.
// Per phase: { ds_read subtile (2 av; phase0 also 8 held bh) ; 1-2 stage
//   issues ; s_barrier ; lgkmcnt(0)+sched_barrier ; setprio(1) ; 8 MFMA ;
//   setprio(0) ; s_barrier }.
// Boundary (between K-tiles): vmcnt(6 if stage(ks+2) issued else 0) +
//   lgkmcnt(0) + sched_barrier + s_barrier.  FIFO per-wave vmcnt order
//   proves stage(ks+1) complete. Ring distance 3 + fenced boundaries close
//   the round-4 race class. Per-phase barriers are scheduling-only (all
//   phases read the current buffer; stage writes a buffer last read one
//   full fenced boundary ago).
// ---------------------------------------------------------------------------
template<int EPI>
__device__ __forceinline__ void gemm_body(const GArgs g, short* smem, int id)
{
  const int t = threadIdx.x;
  const int w = t >> 6;                 // 0..7
  const int lane = t & 63;
  const int l15 = lane & 15, l4 = lane >> 4;
  // 4 bn-blocks sharing an A-panel (same bm) share id%8 -> same XCD.
  const int bm = (EPI == 2) ? id : ((id & 7) | ((id >> 5) << 3));
  const int bn = (EPI == 2) ? 0  : ((id >> 3) & 3);
  const int wm = (w >> 1) * 64;         // 0..192 within 256-row A region
  const int wn = (w & 1) * 64;          // 0/64 within 128-row B region
  const int K = g.K;
  const int NK = K >> 6;                // 2 (K=128) or 8 (K=512)
  f32x4 acc[4][4] = {};

  const int sr = t >> 3;   // 0..63 (row within 64-row round)
  const int ss = t & 7;    // linear 16B slot within 128B row

  auto stageA = [&](int ks, int buf, int q) {
    short* As = smem + buf * 24576;
    int r = q * 64 + sr;
    int c = ss ^ (r & 7);                              // inverse-swizzled slot
    size_t ga = (size_t)(bm * 256 + r) * K + (ks << 6) + c * 8;
    gload16(g.A + ga, &As[q * 4096 + w * 512]);        // wave-uniform LDS base
  };
  auto stageB = [&](int ks, int buf, int q) {
    short* Bs = smem + buf * 24576 + 16384;
    int r = q * 64 + sr;
    int c = ss ^ (r & 7);
    size_t gb = (size_t)(bn * 128 + r) * K + (ks << 6) + c * 8;
    gload16(g.B + gb, &Bs[q * 4096 + w * 512]);
  };
  auto stage_all = [&](int ks, int buf) {
    stageA(ks, buf, 0); stageA(ks, buf, 1); stageA(ks, buf, 2); stageA(ks, buf, 3);
    stageB(ks, buf, 0); stageB(ks, buf, 1);
  };

  // prologue: 2-deep prefetch; vmcnt(6) leaves stage(1) in flight
  stage_all(0, 0);
  stage_all(1, 1);
  asm volatile("s_waitcnt vmcnt(6)" ::: "memory");
  __builtin_amdgcn_sched_barrier(0);
  __builtin_amdgcn_s_barrier();

  for (int ks = 0; ks < NK; ++ks) {
    const short* As = smem + (ks % 3) * 24576;
    const short* Bs = As + 16384;
    const bool st = (ks + 2 < NK);
    const int sb = (ks + 2) % 3;

    short8 bh[4][2];                     // held across the tile's 4 phases

#pragma unroll
    for (int p = 0; p < 4; ++p) {
      // --- ds_read subtile ---
      if (p == 0) {
#pragma unroll
        for (int ni = 0; ni < 4; ++ni) {
          int row = wn + ni * 16 + l15;
          bh[ni][0] = *(const short8*)&Bs[row * 64 + (((0 + l4) ^ (row & 7)) << 3)];
          bh[ni][1] = *(const short8*)&Bs[row * 64 + (((4 + l4) ^ (row & 7)) << 3)];
        }
      }
      int arow = wm + p * 16 + l15;
      short8 av0 = *(const short8*)&As[arow * 64 + (((0 + l4) ^ (arow & 7)) << 3)];
      short8 av1 = *(const short8*)&As[arow * 64 + (((4 + l4) ^ (arow & 7)) << 3)];
      // --- stage issues (spread 6 loads over 4 phases) ---
      if (st) {
        if (p == 0)      { stageA(ks + 2, sb, 0); stageA(ks + 2, sb, 1); }
        else if (p == 1) { stageA(ks + 2, sb, 2); stageA(ks + 2, sb, 3); }
        else if (p == 2) { stageB(ks + 2, sb, 0); }
        else             { stageB(ks + 2, sb, 1); }
      }
      // --- phase sync + MFMA cluster ---
      __builtin_amdgcn_s_barrier();
      asm volatile("s_waitcnt lgkmcnt(0)" ::: "memory");
      __builtin_amdgcn_sched_barrier(0);
      __builtin_amdgcn_s_setprio(1);
#pragma unroll
      for (int ni = 0; ni < 4; ++ni) {
        acc[p][ni] = mf(av0, bh[ni][0], acc[p][ni]);
        acc[p][ni] = mf(av1, bh[ni][1], acc[p][ni]);
      }
      __builtin_amdgcn_s_setprio(0);
      if (p < 3) __builtin_amdgcn_s_barrier();
    }

    // --- tile boundary ---
    if (ks + 1 < NK) {
      if (st) asm volatile("s_waitcnt vmcnt(6)" ::: "memory");
      else    asm volatile("s_waitcnt vmcnt(0)" ::: "memory");
      asm volatile("s_waitcnt lgkmcnt(0)" ::: "memory");
      __builtin_amdgcn_sched_barrier(0);
      __builtin_amdgcn_s_barrier();
    }
  }

  const int gm0 = bm * 256 + wm;
  const int gn0 = bn * 128 + wn;
#pragma unroll
  for (int mi = 0; mi < 4; ++mi) {
#pragma unroll
    for (int ni = 0; ni < 4; ++ni) {
      int n = gn0 + ni * 16 + l15;
#pragma unroll
      for (int r = 0; r < 4; ++r) {
        int m = gm0 + mi * 16 + l4 * 4 + r;
        float v = acc[mi][ni][r];
        if constexpr (EPI == 0) {
          float h = fast_tanh(v + g.bias[n]);
          g.Oh[(size_t)m * UNITS + n] = f2h_bits(h);
        } else if constexpr (EPI == 1) {
          size_t idx = (size_t)m * UNITS + n;
          float h = h2f_bits(g.Hh[idx]);
          g.Oh[idx] = f2h_bits(v * (1.0f - h * h));
        } else {
          if (n < GRAD_COLS)
            g.Og[((size_t)m * NITER + g.iter) * GRAD_COLS + n] = v;
        }
      }
    }
  }
}

template<int EA, int EB>
__global__ __launch_bounds__(512, 2)
void paired_kernel(GArgs A, GArgs B, int nA) {
  __shared__ short smem[73728];        // 3 bufs x (A 16384 + B 8192) = 144KB
  int id = blockIdx.x;
  if (id < nA) gemm_body<EA>(A, smem, id);
  else         gemm_body<EB>(B, smem, id - nA);
}

template<int E>
__global__ __launch_bounds__(512, 2)
void solo_kernel(GArgs A) {
  __shared__ short smem[73728];
  gemm_body<E>(A, smem, blockIdx.x);
}

// ---------------------------------------------------------------------------
// dot (w[:,i] = H3.W4 + b4) + U3 = (1-H3^2)*W4 + build D for iter i+1
// ---------------------------------------------------------------------------
__global__ __launch_bounds__(256)
void dot_bd_kernel(const unsigned short* __restrict__ H3,
                   const float* __restrict__ W4, const float* __restrict__ b4,
                   const float* __restrict__ x, float* __restrict__ w_out,
                   unsigned short* __restrict__ U,
                   unsigned short* __restrict__ D,
                   int iter, int buildD)
{
  int w = threadIdx.x >> 6, lane = threadIdx.x & 63;
  int b = blockIdx.x * 4 + w;
  size_t base = (size_t)b * UNITS + lane * 8;
  short8 vh = *(const short8*)&H3[base];
  float dot = 0.0f;
  short8 ou;
#pragma unroll
  for (int j = 0; j < 8; ++j) {
    float h = h2f_bits((unsigned short)vh[j]);
    float g = W4[lane * 8 + j];
    dot += h * g;
    ou[j] = (short)f2h_bits((1.0f - h * h) * g);
  }
  *(short8*)&U[base] = ou;
#pragma unroll
  for (int off = 1; off < 64; off <<= 1) dot += __shfl_xor(dot, off);
  float wv = dot + b4[0];
  if (lane == 0) w_out[(size_t)b * NITER + iter] = wv;

  if (buildD) {
    int jn = iter + 1;
#pragma unroll
    for (int cc = 0; cc < 2; ++cc) {
      int c = lane + cc * 64;
      float val;
      if (c < 25 - jn)        val = x[(size_t)b * INSZ + jn + c];
      else if (c < 24)        val = w_out[(size_t)b * NITER + (c - (25 - jn))];
      else if (c == 24)       val = wv;      // w[:, jn-1] just computed, in-register
      else if (c < 100)       val = x[(size_t)b * INSZ + 26 + 3 * jn + (c - 25)];
      else if (c == 100)      val = (float)jn;
      else                    val = 0.0f;
      D[(size_t)b * KPAD + c] = f2h_bits(val);
    }
  }
}

// ---------------------------------------------------------------------------
extern "C" void kernel_launch(void* const* d_in, const int* in_sizes, int n_in,
                              void* d_out, int out_size, void* d_ws, size_t ws_size,
                              hipStream_t stream) {
  const float* x  = (const float*)d_in[0];
  const float* W0 = (const float*)d_in[1];
  const float* b0 = (const float*)d_in[2];
  const float* W1 = (const float*)d_in[3];
  const float* b1 = (const float*)d_in[4];
  const float* W2 = (const float*)d_in[5];
  const float* b2 = (const float*)d_in[6];
  const float* W3 = (const float*)d_in[7];
  const float* b3 = (const float*)d_in[8];
  const float* W4 = (const float*)d_in[9];
  const float* b4 = (const float*)d_in[10];

  float* w_out    = (float*)d_out;                              // (8192, 25)
  float* grad_out = (float*)d_out + (size_t)B_ROWS * NITER;     // (8192, 25, 101)

  char* p = (char*)d_ws;
  auto alloc = [&](size_t elems) { unsigned short* r = (unsigned short*)p; p += elems * 2; return r; };

  unsigned short* TW0 = alloc(512 * KPAD);
  unsigned short* TW1 = alloc(512 * 512);
  unsigned short* TW2 = alloc(512 * 512);
  unsigned short* TW3 = alloc(512 * 512);
  unsigned short* CW0 = alloc(KPAD * 512);
  unsigned short* CW1 = alloc(512 * 512);
  unsigned short* CW2 = alloc(512 * 512);
  unsigned short* CW3 = alloc(512 * 512);

  unsigned short* D = alloc((size_t)B_ROWS * KPAD);

  unsigned short *H[2][4];
  for (int par = 0; par < 2; ++par)
    for (int l = 0; l < 4; ++l)
      H[par][l] = alloc((size_t)B_ROWS * UNITS);
  unsigned short* Ua = alloc((size_t)B_ROWS * UNITS);
  unsigned short* Ub = alloc((size_t)B_ROWS * UNITS);

  prep_kernel<<<1024, 256, 0, stream>>>(W0, W1, W2, W3,
      TW0, TW1, TW2, TW3, CW0, CW1, CW2, CW3);

  build_d_kernel<<<4096, 256, 0, stream>>>(x, D);

  // forward chain for iteration 0 (parity 0)
  {
    GArgs f0 = {D, TW0, KPAD, b0, nullptr, H[0][0], nullptr, 0};
    GArgs f1 = {H[0][0], TW1, 512, b1, nullptr, H[0][1], nullptr, 0};
    GArgs f2 = {H[0][1], TW2, 512, b2, nullptr, H[0][2], nullptr, 0};
    GArgs f3 = {H[0][2], TW3, 512, b3, nullptr, H[0][3], nullptr, 0};
    solo_kernel<0><<<128, 512, 0, stream>>>(f0);
    solo_kernel<0><<<128, 512, 0, stream>>>(f1);
    solo_kernel<0><<<128, 512, 0, stream>>>(f2);
    solo_kernel<0><<<128, 512, 0, stream>>>(f3);
  }

  for (int i = 0; i < NITER; ++i) {
    int pp = i & 1, q = pp ^ 1;
    bool more = (i < NITER - 1);

    dot_bd_kernel<<<2048, 256, 0, stream>>>(H[pp][3], W4, b4, x, w_out,
                                            Ua, D, i, more ? 1 : 0);

    GArgs bw3 = {Ua, CW3, 512, nullptr, H[pp][2], Ub, nullptr, 0};
    GArgs bw2 = {Ub, CW2, 512, nullptr, H[pp][1], Ua, nullptr, 0};
    GArgs bw1 = {Ua, CW1, 512, nullptr, H[pp][0], Ub, nullptr, 0};
    GArgs gr0 = {Ub, CW0, 512, nullptr, nullptr, nullptr, grad_out, i};

    if (more) {
      GArgs f0 = {D, TW0, KPAD, b0, nullptr, H[q][0], nullptr, 0};
      GArgs f1 = {H[q][0], TW1, 512, b1, nullptr, H[q][1], nullptr, 0};
      GArgs f2 = {H[q][1], TW2, 512, b2, nullptr, H[q][2], nullptr, 0};
      GArgs f3 = {H[q][2], TW3, 512, b3, nullptr, H[q][3], nullptr, 0};
      paired_kernel<1, 0><<<256, 512, 0, stream>>>(bw3, f0, 128);
      paired_kernel<1, 0><<<256, 512, 0, stream>>>(bw2, f1, 128);
      paired_kernel<1, 0><<<256, 512, 0, stream>>>(bw1, f2, 128);
      paired_kernel<2, 0><<<160, 512, 0, stream>>>(gr0, f3, 32);
    } else {
      solo_kernel<1><<<128, 512, 0, stream>>>(bw3);
      solo_kernel<1><<<128, 512, 0, stream>>>(bw2);
      solo_kernel<1><<<128, 512, 0, stream>>>(bw1);
      solo_kernel<2><<<32, 512, 0, stream>>>(gr0);
    }
  }

  (void)in_sizes; (void)n_in; (void)out_size; (void)ws_size;
}

// Round 10
// 2000.601 us; speedup vs baseline: 1.1410x; 1.1410x over previous
//
#include <hip/hip_runtime.h>

#define B_ROWS 8192
#define UNITS 512
#define NITER 25
#define INSZ 176
#define KPAD 128
#define GRAD_COLS 101

typedef __attribute__((ext_vector_type(8))) short short8;
typedef __attribute__((ext_vector_type(4))) float f32x4;
typedef __attribute__((ext_vector_type(8))) _Float16 half8;

__device__ __forceinline__ unsigned short f2h_bits(float f) {
  _Float16 h = (_Float16)f;
  return __builtin_bit_cast(unsigned short, h);
}
__device__ __forceinline__ float h2f_bits(unsigned short b) {
  return (float)__builtin_bit_cast(_Float16, b);
}
__device__ __forceinline__ float fast_tanh(float x) {
  float e = __expf(2.0f * x);
  return 1.0f - 2.0f / (e + 1.0f);
}

typedef __attribute__((address_space(3))) unsigned int lds_u32;
typedef __attribute__((address_space(1))) const unsigned int glb_u32;
__device__ __forceinline__ void gload16(const void* g, void* l) {
  __builtin_amdgcn_global_load_lds((glb_u32*)g, (lds_u32*)l, 16, 0, 0);
}

__device__ __forceinline__ f32x4 mf(short8 a, short8 b, f32x4 c) {
  return __builtin_amdgcn_mfma_f32_16x16x32_f16(
      __builtin_bit_cast(half8, a), __builtin_bit_cast(half8, b), c, 0, 0, 0);
}

struct GArgs {
  const unsigned short *A;            // activations, fp16 plane, M x K
  const unsigned short *B;            // weights, fp16 plane, N x K (n-major)
  int K;
  const float* bias;
  const unsigned short *Hh;           // fwd activations for EPI1
  unsigned short *Oh;                 // output plane (fp16)
  float* Og;                          // EPI2: grad out; EPI3: w_acc slice
  int iter;                           // EPI2: window base j0
  const float* W4p;                   // EPI3 only
};

// ---------------------------------------------------------------------------
// Weight prep: fp16 planes, n-major layouts, zero-padded. Also zeroes w_acc.
// ---------------------------------------------------------------------------
__global__ __launch_bounds__(256)
void prep_kernel(const float* __restrict__ W0, const float* __restrict__ W1,
                 const float* __restrict__ W2, const float* __restrict__ W3,
                 unsigned short* TW0, unsigned short* TW1,
                 unsigned short* TW2, unsigned short* TW3,
                 unsigned short* CW0, unsigned short* CW1,
                 unsigned short* CW2, unsigned short* CW3,
                 float* w_acc)
{
  int id = blockIdx.x * 256 + threadIdx.x;
  if (id < NITER * B_ROWS) w_acc[id] = 0.0f;
  if (id < 512 * KPAD) {
    int n = id >> 7, k = id & (KPAD - 1);
    TW0[id] = f2h_bits((k < 101) ? W0[(size_t)k * 512 + n] : 0.0f);
    int n2 = id >> 9, k2 = id & 511;
    CW0[id] = f2h_bits((n2 < 101) ? W0[(size_t)n2 * 512 + k2] : 0.0f);
  }
  {
    int n = id >> 9, k = id & 511;
    TW1[id] = f2h_bits(W1[(size_t)k * 512 + n]);
    TW2[id] = f2h_bits(W2[(size_t)k * 512 + n]);
    TW3[id] = f2h_bits(W3[(size_t)k * 512 + n]);
    CW1[id] = f2h_bits(W1[id]);
    CW2[id] = f2h_bits(W2[id]);
    CW3[id] = f2h_bits(W3[id]);
  }
}

// ---------------------------------------------------------------------------
// Initial build D_0 (8192 x 128, fp16), zero-padded cols 101..127
// ---------------------------------------------------------------------------
__global__ __launch_bounds__(256)
void build_d0_kernel(const float* __restrict__ x, unsigned short* __restrict__ D)
{
  int id = blockIdx.x * 256 + threadIdx.x;
  int b = id >> 7, c = id & 127;
  float val;
  if (c < 25)             val = x[(size_t)b * INSZ + c];
  else if (c < 100)       val = x[(size_t)b * INSZ + 26 + (c - 25)];
  else                    val = 0.0f;
  D[id] = f2h_bits(val);
}

// ---------------------------------------------------------------------------
// Forward GEMM: 64x128 tile, BK=64, 4 waves (2m x 2n, 32x64 each), 512 blocks
// (2 blocks/CU), round-6 counted-vmcnt 2-barrier pipeline.
// EPI 0: tanh(acc+bias) -> Oh.
// EPI 3: h = tanh(acc+bias); Oh = (1-h^2)*W4[n] (= U3); w-dot partial
//        shfl-reduced over the 16-lane col group, atomicAdd into Og (w_acc).
// ---------------------------------------------------------------------------
template<int EPI>
__global__ __launch_bounds__(256, 2)
void fwd_kernel(GArgs g)
{
  __shared__ short smem[24576];        // 2 bufs x (A 4096 + B 8192) shorts
  const int t = threadIdx.x;
  const int w = t >> 6;
  const int lane = t & 63;
  const int l15 = lane & 15, l4 = lane >> 4;
  const int id = blockIdx.x;
  const int bm = (id & 7) | ((id >> 5) << 3);   // 0..127 ; 4 bn-blocks of one
  const int bn = (id >> 3) & 3;                 // A-panel share id%8 (XCD)
  const int wm = (w >> 1) * 32, wn = (w & 1) * 64;
  const int K = g.K;
  const int NK = K >> 6;
  f32x4 acc[2][4] = {};

  const int sr = t >> 3;   // 0..31
  const int ss = t & 7;

  auto stage = [&](int ks, int buf) {
    short* As = smem + buf * 12288;
    short* Bs = As + 4096;
    int kc = ks << 6;
#pragma unroll
    for (int q = 0; q < 2; ++q) {                    // A: 64 rows
      int r = q * 32 + sr;
      int c = ss ^ (r & 7);
      size_t ga = (size_t)(bm * 64 + r) * K + kc + c * 8;
      gload16(g.A + ga, &As[q * 2048 + w * 512]);
    }
#pragma unroll
    for (int q = 0; q < 4; ++q) {                    // B: 128 rows
      int r = q * 32 + sr;
      int c = ss ^ (r & 7);
      size_t gb = (size_t)(bn * 128 + r) * K + kc + c * 8;
      gload16(g.B + gb, &Bs[q * 2048 + w * 512]);
    }
  };

  stage(0, 0);
  for (int ks = 0; ks < NK; ++ks) {
    if (ks + 1 < NK) {
      stage(ks + 1, (ks + 1) & 1);
      asm volatile("s_waitcnt vmcnt(6)" ::: "memory");  // only stage(ks)
    } else {
      asm volatile("s_waitcnt vmcnt(0)" ::: "memory");
    }
    __builtin_amdgcn_sched_barrier(0);
    __builtin_amdgcn_s_barrier();

    const short* As = smem + (ks & 1) * 12288;
    const short* Bs = As + 4096;
#pragma unroll
    for (int kk = 0; kk < 2; ++kk) {
      short8 av[2], bh[4];
#pragma unroll
      for (int mi = 0; mi < 2; ++mi) {
        int row = wm + mi * 16 + l15;
        av[mi] = *(const short8*)&As[row * 64 + (((kk * 4 + l4) ^ (row & 7)) << 3)];
      }
#pragma unroll
      for (int ni = 0; ni < 4; ++ni) {
        int row = wn + ni * 16 + l15;
        bh[ni] = *(const short8*)&Bs[row * 64 + (((kk * 4 + l4) ^ (row & 7)) << 3)];
      }
#pragma unroll
      for (int mi = 0; mi < 2; ++mi)
#pragma unroll
        for (int ni = 0; ni < 4; ++ni)
          acc[mi][ni] = mf(av[mi], bh[ni], acc[mi][ni]);
    }
    asm volatile("s_waitcnt lgkmcnt(0)" ::: "memory");
    __builtin_amdgcn_sched_barrier(0);
    __builtin_amdgcn_s_barrier();
  }

  const int gm0 = bm * 64 + wm;
  const int gn0 = bn * 128 + wn;
  float wp[2][4] = {};
#pragma unroll
  for (int mi = 0; mi < 2; ++mi) {
#pragma unroll
    for (int ni = 0; ni < 4; ++ni) {
      int n = gn0 + ni * 16 + l15;
#pragma unroll
      for (int r = 0; r < 4; ++r) {
        int m = gm0 + mi * 16 + l4 * 4 + r;
        float v = acc[mi][ni][r];
        float h = fast_tanh(v + g.bias[n]);
        if constexpr (EPI == 0) {
          g.Oh[(size_t)m * UNITS + n] = f2h_bits(h);
        } else {
          float w4 = g.W4p[n];
          g.Oh[(size_t)m * UNITS + n] = f2h_bits((1.0f - h * h) * w4);
          wp[mi][r] += h * w4;
        }
      }
    }
  }
  if constexpr (EPI == 3) {
    // reduce each wp over the 16-lane col group (lanes share l4 -> same rows)
#pragma unroll
    for (int mi = 0; mi < 2; ++mi)
#pragma unroll
      for (int r = 0; r < 4; ++r) {
        float v = wp[mi][r];
        v += __shfl_xor(v, 1); v += __shfl_xor(v, 2);
        v += __shfl_xor(v, 4); v += __shfl_xor(v, 8);
        if (l15 == 0) {
          int m = gm0 + mi * 16 + l4 * 4 + r;
          atomicAdd(&g.Og[m], v);
        }
      }
  }
}

// ---------------------------------------------------------------------------
// Batched backward GEMM: 128x128 tile, BK=64, 4 waves, round-6 2-phase.
// Grid = wlen*256 (EPI1) or wlen*64 (EPI2): 2-5 blocks/CU.
// EPI 1: acc*(1-h^2) -> Oh (window rows).  EPI 2: grad store, iter = j0.
// ---------------------------------------------------------------------------
template<int EPI>
__global__ __launch_bounds__(256, 2)
void bwd_kernel(GArgs g)
{
  __shared__ short smem[32768];
  const int t = threadIdx.x;
  const int w = t >> 6;
  const int lane = t & 63;
  const int l15 = lane & 15, l4 = lane >> 4;
  const int id = blockIdx.x;
  const int bm = (EPI == 2) ? id : ((id & 7) | ((id >> 5) << 3));
  const int bn = (EPI == 2) ? 0  : ((id >> 3) & 3);
  const int wm = (w >> 1) * 64, wn = (w & 1) * 64;
  const int K = g.K;
  const int NK = K >> 6;
  f32x4 acc[4][4] = {};

  const int sr = t >> 3;
  const int ss = t & 7;

  auto stage = [&](int ks, int buf) {
    short* As = smem + buf * 16384;
    short* Bs = As + 8192;
    int kc = ks << 6;
#pragma unroll
    for (int q = 0; q < 4; ++q) {
      int r = q * 32 + sr;
      int c = ss ^ (r & 7);
      size_t ga = (size_t)(bm * 128 + r) * K + kc + c * 8;
      size_t gb = (size_t)(bn * 128 + r) * K + kc + c * 8;
      int ldst = q * 2048 + w * 512;
      gload16(g.A + ga, &As[ldst]);
      gload16(g.B + gb, &Bs[ldst]);
    }
  };

  stage(0, 0);
  for (int ks = 0; ks < NK; ++ks) {
    if (ks + 1 < NK) {
      stage(ks + 1, (ks + 1) & 1);
      asm volatile("s_waitcnt vmcnt(8)" ::: "memory");
    } else {
      asm volatile("s_waitcnt vmcnt(0)" ::: "memory");
    }
    __builtin_amdgcn_sched_barrier(0);
    __builtin_amdgcn_s_barrier();

    const short* As = smem + (ks & 1) * 16384;
    const short* Bs = As + 8192;
#pragma unroll
    for (int kk = 0; kk < 2; ++kk) {
      short8 av[4], bh[4];
#pragma unroll
      for (int mi = 0; mi < 4; ++mi) {
        int row = wm + mi * 16 + l15;
        av[mi] = *(const short8*)&As[row * 64 + (((kk * 4 + l4) ^ (row & 7)) << 3)];
      }
#pragma unroll
      for (int ni = 0; ni < 4; ++ni) {
        int row = wn + ni * 16 + l15;
        bh[ni] = *(const short8*)&Bs[row * 64 + (((kk * 4 + l4) ^ (row & 7)) << 3)];
      }
#pragma unroll
      for (int mi = 0; mi < 4; ++mi)
#pragma unroll
        for (int ni = 0; ni < 4; ++ni)
          acc[mi][ni] = mf(av[mi], bh[ni], acc[mi][ni]);
    }
    asm volatile("s_waitcnt lgkmcnt(0)" ::: "memory");
    __builtin_amdgcn_sched_barrier(0);
    __builtin_amdgcn_s_barrier();
  }

  const int gm0 = bm * 128 + wm;
  const int gn0 = bn * 128 + wn;
#pragma unroll
  for (int mi = 0; mi < 4; ++mi) {
#pragma unroll
    for (int ni = 0; ni < 4; ++ni) {
      int n = gn0 + ni * 16 + l15;
#pragma unroll
      for (int r = 0; r < 4; ++r) {
        int m = gm0 + mi * 16 + l4 * 4 + r;       // window row
        float v = acc[mi][ni][r];
        if constexpr (EPI == 1) {
          size_t idx = (size_t)m * UNITS + n;
          float h = h2f_bits(g.Hh[idx]);
          g.Oh[idx] = f2h_bits(v * (1.0f - h * h));
        } else {
          if (n < GRAD_COLS) {
            int it = m >> 13, b = m & 8191;
            g.Og[((size_t)b * NITER + (g.iter + it)) * GRAD_COLS + n] = v;
          }
        }
      }
    }
  }
}

// ---------------------------------------------------------------------------
// Per-iter: w_out[b][iter] = w_acc[iter][b] + b4 ; build D(iter+1)
// ---------------------------------------------------------------------------
__global__ __launch_bounds__(256)
void build_dw_kernel(const float* __restrict__ x, const float* __restrict__ w_acc,
                     const float* __restrict__ b4, float* __restrict__ w_out,
                     unsigned short* __restrict__ D, int iter)
{
  int id = blockIdx.x * 256 + threadIdx.x;     // [0, 8192*128)
  int b = id >> 7, c = id & 127;
  float wv = w_acc[(size_t)iter * B_ROWS + b] + b4[0];
  if (c == 0) w_out[(size_t)b * NITER + iter] = wv;
  if (iter < NITER - 1) {
    int jn = iter + 1;
    float val;
    if (c < 25 - jn)        val = x[(size_t)b * INSZ + jn + c];
    else if (c < 24)        val = w_out[(size_t)b * NITER + (c - (25 - jn))];
    else if (c == 24)       val = wv;
    else if (c < 100)       val = x[(size_t)b * INSZ + 26 + 3 * jn + (c - 25)];
    else if (c == 100)      val = (float)jn;
    else                    val = 0.0f;
    D[(size_t)b * KPAD + c] = f2h_bits(val);
  }
}

// ---------------------------------------------------------------------------
extern "C" void kernel_launch(void* const* d_in, const int* in_sizes, int n_in,
                              void* d_out, int out_size, void* d_ws, size_t ws_size,
                              hipStream_t stream) {
  const float* x  = (const float*)d_in[0];
  const float* W0 = (const float*)d_in[1];
  const float* b0 = (const float*)d_in[2];
  const float* W1 = (const float*)d_in[3];
  const float* b1 = (const float*)d_in[4];
  const float* W2 = (const float*)d_in[5];
  const float* b2 = (const float*)d_in[6];
  const float* W3 = (const float*)d_in[7];
  const float* b3 = (const float*)d_in[8];
  const float* W4 = (const float*)d_in[9];
  const float* b4 = (const float*)d_in[10];

  float* w_out    = (float*)d_out;                              // (8192, 25)
  float* grad_out = (float*)d_out + (size_t)B_ROWS * NITER;     // (8192, 25, 101)

  const size_t SL    = (size_t)B_ROWS * UNITS;                  // plane elems
  const size_t FIXED = 3407872 + 2097152 + 819200 + 4096;       // weights+D+w_acc
  int CH = 1;
  {
    const int lad[4] = {25, 5, 3, 2};
    for (int k = 0; k < 4; ++k) {
      size_t need = FIXED + (size_t)lad[k] * 5 * SL * 2;        // 5 planes/iter
      if (ws_size >= need) { CH = lad[k]; break; }
    }
  }

  char* p = (char*)d_ws;
  auto alloc = [&](size_t elems) { unsigned short* r = (unsigned short*)p; p += elems * 2; return r; };

  unsigned short* TW0 = alloc(512 * KPAD);
  unsigned short* TW1 = alloc(512 * 512);
  unsigned short* TW2 = alloc(512 * 512);
  unsigned short* TW3 = alloc(512 * 512);
  unsigned short* CW0 = alloc(KPAD * 512);
  unsigned short* CW1 = alloc(512 * 512);
  unsigned short* CW2 = alloc(512 * 512);
  unsigned short* CW3 = alloc(512 * 512);
  unsigned short* D   = alloc((size_t)B_ROWS * KPAD);
  float* w_acc = (float*)p; p += (size_t)NITER * B_ROWS * 4;

  unsigned short* H0w = alloc((size_t)CH * SL);
  unsigned short* H1w = alloc((size_t)CH * SL);
  unsigned short* H2w = alloc((size_t)CH * SL);
  unsigned short* U3w = alloc((size_t)CH * SL);
  unsigned short* Ubw = alloc((size_t)CH * SL);

  prep_kernel<<<1024, 256, 0, stream>>>(W0, W1, W2, W3,
      TW0, TW1, TW2, TW3, CW0, CW1, CW2, CW3, w_acc);
  build_d0_kernel<<<4096, 256, 0, stream>>>(x, D);

  for (int j0 = 0; j0 < NITER; j0 += CH) {
    int wlen = (NITER - j0 < CH) ? (NITER - j0) : CH;
    // ---- forward chain (sequential) ----
    for (int it = 0; it < wlen; ++it) {
      int i = j0 + it;
      unsigned short* H0s = H0w + (size_t)it * SL;
      unsigned short* H1s = H1w + (size_t)it * SL;
      unsigned short* H2s = H2w + (size_t)it * SL;
      unsigned short* U3s = U3w + (size_t)it * SL;
      GArgs f0 = {D,   TW0, KPAD, b0, nullptr, H0s, nullptr, 0, nullptr};
      GArgs f1 = {H0s, TW1, 512,  b1, nullptr, H1s, nullptr, 0, nullptr};
      GArgs f2 = {H1s, TW2, 512,  b2, nullptr, H2s, nullptr, 0, nullptr};
      GArgs f3 = {H2s, TW3, 512,  b3, nullptr, U3s, w_acc + (size_t)i * B_ROWS, 0, W4};
      fwd_kernel<0><<<512, 256, 0, stream>>>(f0);
      fwd_kernel<0><<<512, 256, 0, stream>>>(f1);
      fwd_kernel<0><<<512, 256, 0, stream>>>(f2);
      fwd_kernel<3><<<512, 256, 0, stream>>>(f3);
      build_dw_kernel<<<4096, 256, 0, stream>>>(x, w_acc, b4, w_out, D, i);
    }
    // ---- batched backward (M = wlen*8192) ----
    GArgs bw3 = {U3w, CW3, 512, nullptr, H2w, Ubw, nullptr, 0, nullptr};
    GArgs bw2 = {Ubw, CW2, 512, nullptr, H1w, U3w, nullptr, 0, nullptr};
    GArgs bw1 = {U3w, CW1, 512, nullptr, H0w, Ubw, nullptr, 0, nullptr};
    GArgs gr0 = {Ubw, CW0, 512, nullptr, nullptr, nullptr, grad_out, j0, nullptr};
    bwd_kernel<1><<<wlen * 256, 256, 0, stream>>>(bw3);
    bwd_kernel<1><<<wlen * 256, 256, 0, stream>>>(bw2);
    bwd_kernel<1><<<wlen * 256, 256, 0, stream>>>(bw1);
    bwd_kernel<2><<<wlen * 64,  256, 0, stream>>>(gr0);
  }

  (void)in_sizes; (void)n_in; (void)out_size;
}

// Round 11
// 1727.504 us; speedup vs baseline: 1.3214x; 1.1581x over previous
//
#include <hip/hip_runtime.h>

#define B_ROWS 8192
#define UNITS 512
#define NITER 25
#define INSZ 176
#define KPAD 128
#define GRAD_COLS 101

typedef __attribute__((ext_vector_type(8))) short short8;
typedef __attribute__((ext_vector_type(4))) float f32x4;
typedef __attribute__((ext_vector_type(8))) _Float16 half8;

__device__ __forceinline__ unsigned short f2h_bits(float f) {
  _Float16 h = (_Float16)f;
  return __builtin_bit_cast(unsigned short, h);
}
__device__ __forceinline__ float h2f_bits(unsigned short b) {
  return (float)__builtin_bit_cast(_Float16, b);
}
__device__ __forceinline__ float fast_tanh(float x) {
  float e = __expf(2.0f * x);
  return 1.0f - 2.0f / (e + 1.0f);
}

typedef __attribute__((address_space(3))) unsigned int lds_u32;
typedef __attribute__((address_space(1))) const unsigned int glb_u32;
__device__ __forceinline__ void gload16(const void* g, void* l) {
  __builtin_amdgcn_global_load_lds((glb_u32*)g, (lds_u32*)l, 16, 0, 0);
}

__device__ __forceinline__ f32x4 mf(short8 a, short8 b, f32x4 c) {
  return __builtin_amdgcn_mfma_f32_16x16x32_f16(
      __builtin_bit_cast(half8, a), __builtin_bit_cast(half8, b), c, 0, 0, 0);
}

struct GArgs {
  const unsigned short *A;            // activations, fp16 plane, M x K
  const unsigned short *B;            // weights, fp16 plane, N x K (n-major)
  int K;
  const float* bias;
  const unsigned short *Hh;           // EPI1: fwd activations
  unsigned short *Oh;                 // output plane (fp16)
  float* Og;                          // EPI2: grad out; EPI3: w_acc slice
  int iter;                           // EPI2 only
  const float* W4p;                   // EPI3 only
};

// ---------------------------------------------------------------------------
// Weight prep: fp16 planes, n-major layouts, zero-padded. Zeroes w_acc
// (required every call: EPI3 accumulates into it; harness replays).
// ---------------------------------------------------------------------------
__global__ __launch_bounds__(256)
void prep_kernel(const float* __restrict__ W0, const float* __restrict__ W1,
                 const float* __restrict__ W2, const float* __restrict__ W3,
                 unsigned short* TW0, unsigned short* TW1,
                 unsigned short* TW2, unsigned short* TW3,
                 unsigned short* CW0, unsigned short* CW1,
                 unsigned short* CW2, unsigned short* CW3,
                 float* w_acc)
{
  int id = blockIdx.x * 256 + threadIdx.x;
  if (id < NITER * B_ROWS) w_acc[id] = 0.0f;
  if (id < 512 * KPAD) {
    int n = id >> 7, k = id & (KPAD - 1);
    TW0[id] = f2h_bits((k < 101) ? W0[(size_t)k * 512 + n] : 0.0f);
    int n2 = id >> 9, k2 = id & 511;
    CW0[id] = f2h_bits((n2 < 101) ? W0[(size_t)n2 * 512 + k2] : 0.0f);
  }
  {
    int n = id >> 9, k = id & 511;
    TW1[id] = f2h_bits(W1[(size_t)k * 512 + n]);
    TW2[id] = f2h_bits(W2[(size_t)k * 512 + n]);
    TW3[id] = f2h_bits(W3[(size_t)k * 512 + n]);
    CW1[id] = f2h_bits(W1[id]);
    CW2[id] = f2h_bits(W2[id]);
    CW3[id] = f2h_bits(W3[id]);
  }
}

// ---------------------------------------------------------------------------
// Initial build D_0 (8192 x 128, fp16), zero-padded cols 101..127
// ---------------------------------------------------------------------------
__global__ __launch_bounds__(256)
void build_d0_kernel(const float* __restrict__ x, unsigned short* __restrict__ D)
{
  int id = blockIdx.x * 256 + threadIdx.x;
  int b = id >> 7, c = id & 127;
  float val;
  if (c < 25)             val = x[(size_t)b * INSZ + c];
  else if (c < 100)       val = x[(size_t)b * INSZ + 26 + (c - 25)];
  else                    val = 0.0f;
  D[id] = f2h_bits(val);
}

// ---------------------------------------------------------------------------
// Unified GEMM body: C[M x N] = A[M x K] @ B(n-major)[N x K], fp16.
// 64x128 tile, BK=64, 4 waves (2m x 2n, 32x64 each), 48KB LDS double-buffer
// -> 3 blocks/CU co-residency (the measured-best regime: ~565 TF round 10).
// Round-6 counted-vmcnt 2-barrier pipeline (replay-verified).
// EPI 0: tanh(acc+bias) -> Oh
// EPI 1: acc*(1-h^2), h from Hh -> Oh
// EPI 2: grad store (bn==0 grid, n<101), iter
// EPI 3: h = tanh(acc+bias); Oh = (1-h^2)*W4[n]; w-dot partials reduced over
//        the 16-lane col group, atomicAdd into Og (w_acc row block)
// ---------------------------------------------------------------------------
template<int EPI>
__device__ __forceinline__ void gemm64(const GArgs g, short* smem, int id)
{
  const int t = threadIdx.x;
  const int w = t >> 6;
  const int lane = t & 63;
  const int l15 = lane & 15, l4 = lane >> 4;
  const int bm = (EPI == 2) ? id : ((id & 7) | ((id >> 5) << 3));
  const int bn = (EPI == 2) ? 0  : ((id >> 3) & 3);
  const int wm = (w >> 1) * 32, wn = (w & 1) * 64;
  const int K = g.K;
  const int NK = K >> 6;
  f32x4 acc[2][4] = {};

  const int sr = t >> 3;   // 0..31
  const int ss = t & 7;

  auto stage = [&](int ks, int buf) {
    short* As = smem + buf * 12288;
    short* Bs = As + 4096;
    int kc = ks << 6;
#pragma unroll
    for (int q = 0; q < 2; ++q) {                    // A: 64 rows
      int r = q * 32 + sr;
      int c = ss ^ (r & 7);
      size_t ga = (size_t)(bm * 64 + r) * K + kc + c * 8;
      gload16(g.A + ga, &As[q * 2048 + w * 512]);
    }
#pragma unroll
    for (int q = 0; q < 4; ++q) {                    // B: 128 rows
      int r = q * 32 + sr;
      int c = ss ^ (r & 7);
      size_t gb = (size_t)(bn * 128 + r) * K + kc + c * 8;
      gload16(g.B + gb, &Bs[q * 2048 + w * 512]);
    }
  };

  stage(0, 0);
  for (int ks = 0; ks < NK; ++ks) {
    if (ks + 1 < NK) {
      stage(ks + 1, (ks + 1) & 1);
      asm volatile("s_waitcnt vmcnt(6)" ::: "memory");  // only stage(ks)
    } else {
      asm volatile("s_waitcnt vmcnt(0)" ::: "memory");
    }
    __builtin_amdgcn_sched_barrier(0);
    __builtin_amdgcn_s_barrier();

    const short* As = smem + (ks & 1) * 12288;
    const short* Bs = As + 4096;
#pragma unroll
    for (int kk = 0; kk < 2; ++kk) {
      short8 av[2], bh[4];
#pragma unroll
      for (int mi = 0; mi < 2; ++mi) {
        int row = wm + mi * 16 + l15;
        av[mi] = *(const short8*)&As[row * 64 + (((kk * 4 + l4) ^ (row & 7)) << 3)];
      }
#pragma unroll
      for (int ni = 0; ni < 4; ++ni) {
        int row = wn + ni * 16 + l15;
        bh[ni] = *(const short8*)&Bs[row * 64 + (((kk * 4 + l4) ^ (row & 7)) << 3)];
      }
#pragma unroll
      for (int mi = 0; mi < 2; ++mi)
#pragma unroll
        for (int ni = 0; ni < 4; ++ni)
          acc[mi][ni] = mf(av[mi], bh[ni], acc[mi][ni]);
    }
    asm volatile("s_waitcnt lgkmcnt(0)" ::: "memory");
    __builtin_amdgcn_sched_barrier(0);
    __builtin_amdgcn_s_barrier();
  }

  const int gm0 = bm * 64 + wm;
  const int gn0 = bn * 128 + wn;
  float wp[2][4] = {};
#pragma unroll
  for (int mi = 0; mi < 2; ++mi) {
#pragma unroll
    for (int ni = 0; ni < 4; ++ni) {
      int n = gn0 + ni * 16 + l15;
#pragma unroll
      for (int r = 0; r < 4; ++r) {
        int m = gm0 + mi * 16 + l4 * 4 + r;
        float v = acc[mi][ni][r];
        if constexpr (EPI == 0) {
          float h = fast_tanh(v + g.bias[n]);
          g.Oh[(size_t)m * UNITS + n] = f2h_bits(h);
        } else if constexpr (EPI == 1) {
          size_t idx = (size_t)m * UNITS + n;
          float h = h2f_bits(g.Hh[idx]);
          g.Oh[idx] = f2h_bits(v * (1.0f - h * h));
        } else if constexpr (EPI == 2) {
          if (n < GRAD_COLS)
            g.Og[((size_t)m * NITER + g.iter) * GRAD_COLS + n] = v;
        } else {
          float h = fast_tanh(v + g.bias[n]);
          float w4 = g.W4p[n];
          g.Oh[(size_t)m * UNITS + n] = f2h_bits((1.0f - h * h) * w4);
          wp[mi][r] += h * w4;
        }
      }
    }
  }
  if constexpr (EPI == 3) {
#pragma unroll
    for (int mi = 0; mi < 2; ++mi)
#pragma unroll
      for (int r = 0; r < 4; ++r) {
        float v = wp[mi][r];
        v += __shfl_xor(v, 1); v += __shfl_xor(v, 2);
        v += __shfl_xor(v, 4); v += __shfl_xor(v, 8);
        if (l15 == 0) {
          int m = gm0 + mi * 16 + l4 * 4 + r;
          atomicAdd(&g.Og[m], v);
        }
      }
  }
}

template<int EA, int EB>
__global__ __launch_bounds__(256, 3)
void paired_kernel(GArgs A, GArgs B, int nA) {
  __shared__ short smem[24576];        // 48KB -> 3 blocks/CU
  int id = blockIdx.x;
  if (id < nA) gemm64<EA>(A, smem, id);
  else         gemm64<EB>(B, smem, id - nA);
}

template<int E>
__global__ __launch_bounds__(256, 3)
void solo_kernel(GArgs A) {
  __shared__ short smem[24576];
  gemm64<E>(A, smem, blockIdx.x);
}

// ---------------------------------------------------------------------------
// Per-iter: w_out[b][iter] = w_acc[iter][b] + b4 ; build D(iter+1)
// ---------------------------------------------------------------------------
__global__ __launch_bounds__(256)
void build_dw_kernel(const float* __restrict__ x, const float* __restrict__ w_acc,
                     const float* __restrict__ b4, float* __restrict__ w_out,
                     unsigned short* __restrict__ D, int iter)
{
  int id = blockIdx.x * 256 + threadIdx.x;     // [0, 8192*128)
  int b = id >> 7, c = id & 127;
  float wv = w_acc[(size_t)iter * B_ROWS + b] + b4[0];
  if (c == 0) w_out[(size_t)b * NITER + iter] = wv;
  if (iter < NITER - 1) {
    int jn = iter + 1;
    float val;
    if (c < 25 - jn)        val = x[(size_t)b * INSZ + jn + c];
    else if (c < 24)        val = w_out[(size_t)b * NITER + (c - (25 - jn))];
    else if (c == 24)       val = wv;
    else if (c < 100)       val = x[(size_t)b * INSZ + 26 + 3 * jn + (c - 25)];
    else if (c == 100)      val = (float)jn;
    else                    val = 0.0f;
    D[(size_t)b * KPAD + c] = f2h_bits(val);
  }
}

// ---------------------------------------------------------------------------
extern "C" void kernel_launch(void* const* d_in, const int* in_sizes, int n_in,
                              void* d_out, int out_size, void* d_ws, size_t ws_size,
                              hipStream_t stream) {
  const float* x  = (const float*)d_in[0];
  const float* W0 = (const float*)d_in[1];
  const float* b0 = (const float*)d_in[2];
  const float* W1 = (const float*)d_in[3];
  const float* b1 = (const float*)d_in[4];
  const float* W2 = (const float*)d_in[5];
  const float* b2 = (const float*)d_in[6];
  const float* W3 = (const float*)d_in[7];
  const float* b3 = (const float*)d_in[8];
  const float* W4 = (const float*)d_in[9];
  const float* b4 = (const float*)d_in[10];

  float* w_out    = (float*)d_out;                              // (8192, 25)
  float* grad_out = (float*)d_out + (size_t)B_ROWS * NITER;     // (8192, 25, 101)

  char* p = (char*)d_ws;
  auto alloc = [&](size_t elems) { unsigned short* r = (unsigned short*)p; p += elems * 2; return r; };

  unsigned short* TW0 = alloc(512 * KPAD);
  unsigned short* TW1 = alloc(512 * 512);
  unsigned short* TW2 = alloc(512 * 512);
  unsigned short* TW3 = alloc(512 * 512);
  unsigned short* CW0 = alloc(KPAD * 512);
  unsigned short* CW1 = alloc(512 * 512);
  unsigned short* CW2 = alloc(512 * 512);
  unsigned short* CW3 = alloc(512 * 512);
  unsigned short* D   = alloc((size_t)B_ROWS * KPAD);
  float* w_acc = (float*)p; p += (size_t)NITER * B_ROWS * 4;

  const size_t SL = (size_t)B_ROWS * UNITS;
  unsigned short *H0[2], *H1[2], *H2[2], *U3[2];
  for (int par = 0; par < 2; ++par) {
    H0[par] = alloc(SL); H1[par] = alloc(SL);
    H2[par] = alloc(SL); U3[par] = alloc(SL);
  }
  unsigned short* Ub = alloc(SL);
  unsigned short* Uc = alloc(SL);

  prep_kernel<<<1024, 256, 0, stream>>>(W0, W1, W2, W3,
      TW0, TW1, TW2, TW3, CW0, CW1, CW2, CW3, w_acc);
  build_d0_kernel<<<4096, 256, 0, stream>>>(x, D);

  // prologue: forward chain for iteration 0 (parity 0)
  {
    GArgs f0 = {D, TW0, KPAD, b0, nullptr, H0[0], nullptr, 0, nullptr};
    GArgs f1 = {H0[0], TW1, 512, b1, nullptr, H1[0], nullptr, 0, nullptr};
    GArgs f2 = {H1[0], TW2, 512, b2, nullptr, H2[0], nullptr, 0, nullptr};
    GArgs f3 = {H2[0], TW3, 512, b3, nullptr, U3[0], w_acc, 0, W4};
    solo_kernel<0><<<512, 256, 0, stream>>>(f0);
    solo_kernel<0><<<512, 256, 0, stream>>>(f1);
    solo_kernel<0><<<512, 256, 0, stream>>>(f2);
    solo_kernel<3><<<512, 256, 0, stream>>>(f3);
  }

  for (int i = 0; i < NITER; ++i) {
    int pp = i & 1, q = pp ^ 1;
    bool more = (i < NITER - 1);

    // w_out[:,i] from w_acc (f3(i) done), build D(i+1)
    build_dw_kernel<<<4096, 256, 0, stream>>>(x, w_acc, b4, w_out, D, i);

    GArgs bw3 = {U3[pp], CW3, 512, nullptr, H2[pp], Ub, nullptr, 0, nullptr};
    GArgs bw2 = {Ub,     CW2, 512, nullptr, H1[pp], Uc, nullptr, 0, nullptr};
    GArgs bw1 = {Uc,     CW1, 512, nullptr, H0[pp], Ub, nullptr, 0, nullptr};
    GArgs gr0 = {Ub,     CW0, 512, nullptr, nullptr, nullptr, grad_out, i, nullptr};

    if (more) {
      GArgs f0 = {D, TW0, KPAD, b0, nullptr, H0[q], nullptr, 0, nullptr};
      GArgs f1 = {H0[q], TW1, 512, b1, nullptr, H1[q], nullptr, 0, nullptr};
      GArgs f2 = {H1[q], TW2, 512, b2, nullptr, H2[q], nullptr, 0, nullptr};
      GArgs f3 = {H2[q], TW3, 512, b3, nullptr, U3[q],
                  w_acc + (size_t)(i + 1) * B_ROWS, 0, W4};
      paired_kernel<1, 0><<<1024, 256, 0, stream>>>(bw3, f0, 512);
      paired_kernel<1, 0><<<1024, 256, 0, stream>>>(bw2, f1, 512);
      paired_kernel<1, 0><<<1024, 256, 0, stream>>>(bw1, f2, 512);
      paired_kernel<2, 3><<<640,  256, 0, stream>>>(gr0, f3, 128);
    } else {
      solo_kernel<1><<<512, 256, 0, stream>>>(bw3);
      solo_kernel<1><<<512, 256, 0, stream>>>(bw2);
      solo_kernel<1><<<512, 256, 0, stream>>>(bw1);
      solo_kernel<2><<<128, 256, 0, stream>>>(gr0);
    }
  }

  (void)in_sizes; (void)n_in; (void)out_size; (void)ws_size;
}

// Round 12
// 1720.968 us; speedup vs baseline: 1.3264x; 1.0038x over previous
//
#include <hip/hip_runtime.h>

#define B_ROWS 8192
#define UNITS 512
#define NITER 25
#define INSZ 176
#define KPAD 128
#define GRAD_COLS 101

typedef __attribute__((ext_vector_type(8))) short short8;
typedef __attribute__((ext_vector_type(4))) float f32x4;
typedef __attribute__((ext_vector_type(8))) _Float16 half8;

__device__ __forceinline__ unsigned short f2h_bits(float f) {
  _Float16 h = (_Float16)f;
  return __builtin_bit_cast(unsigned short, h);
}
__device__ __forceinline__ float h2f_bits(unsigned short b) {
  return (float)__builtin_bit_cast(_Float16, b);
}
__device__ __forceinline__ float fast_tanh(float x) {
  float e = __expf(2.0f * x);
  return 1.0f - 2.0f / (e + 1.0f);
}

typedef __attribute__((address_space(3))) unsigned int lds_u32;
typedef __attribute__((address_space(1))) const unsigned int glb_u32;
__device__ __forceinline__ void gload16(const void* g, void* l) {
  __builtin_amdgcn_global_load_lds((glb_u32*)g, (lds_u32*)l, 16, 0, 0);
}

__device__ __forceinline__ f32x4 mf(short8 a, short8 b, f32x4 c) {
  return __builtin_amdgcn_mfma_f32_16x16x32_f16(
      __builtin_bit_cast(half8, a), __builtin_bit_cast(half8, b), c, 0, 0, 0);
}

struct GArgs {
  const unsigned short *A;            // activations plane, M x K (EPI != 4)
  const unsigned short *B;            // weights plane, N x K (n-major)
  int K;
  const float* bias;
  const unsigned short *Hh;           // EPI1: fwd activations
  unsigned short *Oh;                 // output plane (fp16)
  float* Og;                          // EPI2: grad out; EPI3: w_acc slice
  int iter;                           // EPI2: iter; EPI4: iteration i
  const float* W4p;                   // EPI3
  const float* xp;                    // EPI4
  float* woutp;                       // EPI4: writes col iter-1; EPI2-final: col 24
  const float* waccp;                 // EPI4: w_acc row (iter-1); EPI2-final: row 24
  const float* b4p;                   // EPI4 / EPI2-final
};

// ---------------------------------------------------------------------------
// Weight prep: fp16 planes, n-major layouts, zero-padded. Zeroes w_acc
// (required every call: EPI3 accumulates into it; harness replays).
// ---------------------------------------------------------------------------
__global__ __launch_bounds__(256)
void prep_kernel(const float* __restrict__ W0, const float* __restrict__ W1,
                 const float* __restrict__ W2, const float* __restrict__ W3,
                 unsigned short* TW0, unsigned short* TW1,
                 unsigned short* TW2, unsigned short* TW3,
                 unsigned short* CW0, unsigned short* CW1,
                 unsigned short* CW2, unsigned short* CW3,
                 float* w_acc)
{
  int id = blockIdx.x * 256 + threadIdx.x;
  if (id < NITER * B_ROWS) w_acc[id] = 0.0f;
  if (id < 512 * KPAD) {
    int n = id >> 7, k = id & (KPAD - 1);
    TW0[id] = f2h_bits((k < 101) ? W0[(size_t)k * 512 + n] : 0.0f);
    int n2 = id >> 9, k2 = id & 511;
    CW0[id] = f2h_bits((n2 < 101) ? W0[(size_t)n2 * 512 + k2] : 0.0f);
  }
  {
    int n = id >> 9, k = id & 511;
    TW1[id] = f2h_bits(W1[(size_t)k * 512 + n]);
    TW2[id] = f2h_bits(W2[(size_t)k * 512 + n]);
    TW3[id] = f2h_bits(W3[(size_t)k * 512 + n]);
    CW1[id] = f2h_bits(W1[id]);
    CW2[id] = f2h_bits(W2[id]);
    CW3[id] = f2h_bits(W3[id]);
  }
}

// ---------------------------------------------------------------------------
// Unified GEMM body: C[M x N] = A[M x K] @ B(n-major)[N x K], fp16.
// 64x128 tile, BK=64, 4 waves (2m x 2n, 32x64 each), 48KB LDS
// -> 3 blocks/CU (measured-best regime). Counted-vmcnt 2-barrier pipeline.
// EPI 0: tanh(acc+bias) -> Oh
// EPI 1: acc*(1-h^2), h from Hh -> Oh
// EPI 2: grad store (bn==0 grid, n<101); optional final w_out[:,24] write
// EPI 3: h=tanh(acc+bias); Oh=(1-h^2)*W4[n]; w-dot -> atomicAdd w_acc
// EPI 4: f0 with ON-THE-FLY A: builds D-tile in LDS from x/w_out/w_acc
//        (A staged once, 16KB; B double-buffered 2x16KB; vmcnt(4) boundary).
//        Also writes w_out[:, iter-1] (bn==0, ss==0 lanes).
// ---------------------------------------------------------------------------
template<int EPI>
__device__ __forceinline__ void gemm64(const GArgs g, short* smem, int id)
{
  const int t = threadIdx.x;
  const int w = t >> 6;
  const int lane = t & 63;
  const int l15 = lane & 15, l4 = lane >> 4;
  const int bm = (EPI == 2) ? id : ((id & 7) | ((id >> 5) << 3));
  const int bn = (EPI == 2) ? 0  : ((id >> 3) & 3);
  const int wm = (w >> 1) * 32, wn = (w & 1) * 64;
  const int K = g.K;
  const int NK = K >> 6;
  f32x4 acc[2][4] = {};

  const int sr = t >> 3;   // 0..31
  const int ss = t & 7;

  // --- EPI4: build the 64x128 A-tile (D) in LDS, swizzled slot layout ---
  if constexpr (EPI == 4) {
    const int i = g.iter;
#pragma unroll
    for (int q = 0; q < 2; ++q) {
      int r = q * 32 + sr;
      int b = bm * 64 + r;
      float wv = (i > 0) ? (g.waccp[b] + g.b4p[0]) : 0.0f;
      if (i > 0 && ss == 0 && bn == 0)
        g.woutp[(size_t)b * NITER + (i - 1)] = wv;
      int cc = (ss ^ (r & 7)) << 3;            // global col base for this slot
#pragma unroll
      for (int half = 0; half < 2; ++half) {
        short8 vals;
#pragma unroll
        for (int j = 0; j < 8; ++j) {
          int col = half * 64 + cc + j;
          float val;
          if (col < 25 - i)       val = g.xp[(size_t)b * INSZ + i + col];
          else if (col < 24)      val = g.woutp[(size_t)b * NITER + (col - (25 - i))];
          else if (col == 24)     val = wv;
          else if (col < 100)     val = g.xp[(size_t)b * INSZ + 26 + 3 * i + (col - 25)];
          else if (col == 100)    val = (float)i;
          else                    val = 0.0f;
          vals[j] = (short)f2h_bits(val);
        }
        *(short8*)&smem[half * 4096 + r * 64 + ss * 8] = vals;
      }
    }
  }

  // stage: EPI4 -> B only (4 gloads, bufs at smem+8192); else A+B (6 gloads)
  auto stage = [&](int ks, int buf) {
    int kc = ks << 6;
    if constexpr (EPI != 4) {
      short* As = smem + buf * 12288;
      short* Bs = As + 4096;
#pragma unroll
      for (int q = 0; q < 2; ++q) {                  // A: 64 rows
        int r = q * 32 + sr;
        int c = ss ^ (r & 7);
        size_t ga = (size_t)(bm * 64 + r) * K + kc + c * 8;
        gload16(g.A + ga, &As[q * 2048 + w * 512]);
      }
#pragma unroll
      for (int q = 0; q < 4; ++q) {                  // B: 128 rows
        int r = q * 32 + sr;
        int c = ss ^ (r & 7);
        size_t gb = (size_t)(bn * 128 + r) * K + kc + c * 8;
        gload16(g.B + gb, &Bs[q * 2048 + w * 512]);
      }
    } else {
      short* Bs = smem + 8192 + buf * 8192;
#pragma unroll
      for (int q = 0; q < 4; ++q) {
        int r = q * 32 + sr;
        int c = ss ^ (r & 7);
        size_t gb = (size_t)(bn * 128 + r) * K + kc + c * 8;
        gload16(g.B + gb, &Bs[q * 2048 + w * 512]);
      }
    }
  };

  stage(0, 0);
  for (int ks = 0; ks < NK; ++ks) {
    if (ks + 1 < NK) {
      stage(ks + 1, (ks + 1) & 1);
      if constexpr (EPI == 4) asm volatile("s_waitcnt vmcnt(4)" ::: "memory");
      else                    asm volatile("s_waitcnt vmcnt(6)" ::: "memory");
    } else {
      asm volatile("s_waitcnt vmcnt(0)" ::: "memory");
    }
    // leading lgkm drain: EPI4 ks==0 needs A-build ds_writes visible;
    // otherwise free (trailing edge already drained to 0).
    asm volatile("s_waitcnt lgkmcnt(0)" ::: "memory");
    __builtin_amdgcn_sched_barrier(0);
    __builtin_amdgcn_s_barrier();

    const short* As = (EPI == 4) ? (smem + ks * 4096) : (smem + (ks & 1) * 12288);
    const short* Bs = (EPI == 4) ? (smem + 8192 + (ks & 1) * 8192) : (As + 4096);
#pragma unroll
    for (int kk = 0; kk < 2; ++kk) {
      short8 av[2], bh[4];
#pragma unroll
      for (int mi = 0; mi < 2; ++mi) {
        int row = wm + mi * 16 + l15;
        av[mi] = *(const short8*)&As[row * 64 + (((kk * 4 + l4) ^ (row & 7)) << 3)];
      }
#pragma unroll
      for (int ni = 0; ni < 4; ++ni) {
        int row = wn + ni * 16 + l15;
        bh[ni] = *(const short8*)&Bs[row * 64 + (((kk * 4 + l4) ^ (row & 7)) << 3)];
      }
#pragma unroll
      for (int mi = 0; mi < 2; ++mi)
#pragma unroll
        for (int ni = 0; ni < 4; ++ni)
          acc[mi][ni] = mf(av[mi], bh[ni], acc[mi][ni]);
    }
    asm volatile("s_waitcnt lgkmcnt(0)" ::: "memory");
    __builtin_amdgcn_sched_barrier(0);
    __builtin_amdgcn_s_barrier();
  }

  const int gm0 = bm * 64 + wm;
  const int gn0 = bn * 128 + wn;
  float wp[2][4] = {};
#pragma unroll
  for (int mi = 0; mi < 2; ++mi) {
#pragma unroll
    for (int ni = 0; ni < 4; ++ni) {
      int n = gn0 + ni * 16 + l15;
#pragma unroll
      for (int r = 0; r < 4; ++r) {
        int m = gm0 + mi * 16 + l4 * 4 + r;
        float v = acc[mi][ni][r];
        if constexpr (EPI == 0 || EPI == 4) {
          float h = fast_tanh(v + g.bias[n]);
          g.Oh[(size_t)m * UNITS + n] = f2h_bits(h);
        } else if constexpr (EPI == 1) {
          size_t idx = (size_t)m * UNITS + n;
          float h = h2f_bits(g.Hh[idx]);
          g.Oh[idx] = f2h_bits(v * (1.0f - h * h));
        } else if constexpr (EPI == 2) {
          if (n < GRAD_COLS)
            g.Og[((size_t)m * NITER + g.iter) * GRAD_COLS + n] = v;
        } else {
          float h = fast_tanh(v + g.bias[n]);
          float w4 = g.W4p[n];
          g.Oh[(size_t)m * UNITS + n] = f2h_bits((1.0f - h * h) * w4);
          wp[mi][r] += h * w4;
        }
      }
    }
  }
  if constexpr (EPI == 3) {
#pragma unroll
    for (int mi = 0; mi < 2; ++mi)
#pragma unroll
      for (int r = 0; r < 4; ++r) {
        float v = wp[mi][r];
        v += __shfl_xor(v, 1); v += __shfl_xor(v, 2);
        v += __shfl_xor(v, 4); v += __shfl_xor(v, 8);
        if (l15 == 0) {
          int m = gm0 + mi * 16 + l4 * 4 + r;
          atomicAdd(&g.Og[m], v);
        }
      }
  }
  if constexpr (EPI == 2) {
    // final iteration only: w_out[:,24] = w_acc[24] + b4
    if (g.woutp && wn == 0 && l15 == 0) {
#pragma unroll
      for (int mi = 0; mi < 2; ++mi)
#pragma unroll
        for (int r = 0; r < 4; ++r) {
          int m = gm0 + mi * 16 + l4 * 4 + r;
          g.woutp[(size_t)m * NITER + 24] = g.waccp[m] + g.b4p[0];
        }
    }
  }
}

template<int EA, int EB>
__global__ __launch_bounds__(256, 3)
void paired_kernel(GArgs A, GArgs B, int nA) {
  __shared__ short smem[24576];        // 48KB -> 3 blocks/CU
  int id = blockIdx.x;
  if (id < nA) gemm64<EA>(A, smem, id);
  else         gemm64<EB>(B, smem, id - nA);
}

template<int E>
__global__ __launch_bounds__(256, 3)
void solo_kernel(GArgs A) {
  __shared__ short smem[24576];
  gemm64<E>(A, smem, blockIdx.x);
}

// ---------------------------------------------------------------------------
extern "C" void kernel_launch(void* const* d_in, const int* in_sizes, int n_in,
                              void* d_out, int out_size, void* d_ws, size_t ws_size,
                              hipStream_t stream) {
  const float* x  = (const float*)d_in[0];
  const float* W0 = (const float*)d_in[1];
  const float* b0 = (const float*)d_in[2];
  const float* W1 = (const float*)d_in[3];
  const float* b1 = (const float*)d_in[4];
  const float* W2 = (const float*)d_in[5];
  const float* b2 = (const float*)d_in[6];
  const float* W3 = (const float*)d_in[7];
  const float* b3 = (const float*)d_in[8];
  const float* W4 = (const float*)d_in[9];
  const float* b4 = (const float*)d_in[10];

  float* w_out    = (float*)d_out;                              // (8192, 25)
  float* grad_out = (float*)d_out + (size_t)B_ROWS * NITER;     // (8192, 25, 101)

  char* p = (char*)d_ws;
  auto alloc = [&](size_t elems) { unsigned short* r = (unsigned short*)p; p += elems * 2; return r; };

  unsigned short* TW0 = alloc(512 * KPAD);
  unsigned short* TW1 = alloc(512 * 512);
  unsigned short* TW2 = alloc(512 * 512);
  unsigned short* TW3 = alloc(512 * 512);
  unsigned short* CW0 = alloc(KPAD * 512);
  unsigned short* CW1 = alloc(512 * 512);
  unsigned short* CW2 = alloc(512 * 512);
  unsigned short* CW3 = alloc(512 * 512);
  float* w_acc = (float*)p; p += (size_t)NITER * B_ROWS * 4;

  const size_t SL = (size_t)B_ROWS * UNITS;
  unsigned short *H0[2], *H1[2], *H2[2], *U3[2];
  for (int par = 0; par < 2; ++par) {
    H0[par] = alloc(SL); H1[par] = alloc(SL);
    H2[par] = alloc(SL); U3[par] = alloc(SL);
  }
  unsigned short* Ub = alloc(SL);
  unsigned short* Uc = alloc(SL);

  prep_kernel<<<1024, 256, 0, stream>>>(W0, W1, W2, W3,
      TW0, TW1, TW2, TW3, CW0, CW1, CW2, CW3, w_acc);

  // prologue: forward chain for iteration 0 (parity 0); f0 builds D on the fly
  {
    GArgs f0 = {nullptr, TW0, KPAD, b0, nullptr, H0[0], nullptr, 0, nullptr,
                x, w_out, w_acc, b4};
    GArgs f1 = {H0[0], TW1, 512, b1, nullptr, H1[0], nullptr, 0, nullptr,
                nullptr, nullptr, nullptr, nullptr};
    GArgs f2 = {H1[0], TW2, 512, b2, nullptr, H2[0], nullptr, 0, nullptr,
                nullptr, nullptr, nullptr, nullptr};
    GArgs f3 = {H2[0], TW3, 512, b3, nullptr, U3[0], w_acc, 0, W4,
                nullptr, nullptr, nullptr, nullptr};
    solo_kernel<4><<<512, 256, 0, stream>>>(f0);
    solo_kernel<0><<<512, 256, 0, stream>>>(f1);
    solo_kernel<0><<<512, 256, 0, stream>>>(f2);
    solo_kernel<3><<<512, 256, 0, stream>>>(f3);
  }

  for (int i = 0; i < NITER; ++i) {
    int pp = i & 1, q = pp ^ 1;
    bool more = (i < NITER - 1);
    bool last = (i == NITER - 1);

    GArgs bw3 = {U3[pp], CW3, 512, nullptr, H2[pp], Ub, nullptr, 0, nullptr,
                 nullptr, nullptr, nullptr, nullptr};
    GArgs bw2 = {Ub,     CW2, 512, nullptr, H1[pp], Uc, nullptr, 0, nullptr,
                 nullptr, nullptr, nullptr, nullptr};
    GArgs bw1 = {Uc,     CW1, 512, nullptr, H0[pp], Ub, nullptr, 0, nullptr,
                 nullptr, nullptr, nullptr, nullptr};
    GArgs gr0 = {Ub,     CW0, 512, nullptr, nullptr, nullptr, grad_out, i, nullptr,
                 nullptr,
                 last ? w_out : nullptr,
                 last ? (w_acc + (size_t)24 * B_ROWS) : nullptr,
                 last ? b4 : nullptr};

    if (more) {
      // f-chain for iteration i+1; f0 builds D(i+1) on the fly and writes w_out[:,i]
      GArgs f0 = {nullptr, TW0, KPAD, b0, nullptr, H0[q], nullptr, i + 1, nullptr,
                  x, w_out, w_acc + (size_t)i * B_ROWS, b4};
      GArgs f1 = {H0[q], TW1, 512, b1, nullptr, H1[q], nullptr, 0, nullptr,
                  nullptr, nullptr, nullptr, nullptr};
      GArgs f2 = {H1[q], TW2, 512, b2, nullptr, H2[q], nullptr, 0, nullptr,
                  nullptr, nullptr, nullptr, nullptr};
      GArgs f3 = {H2[q], TW3, 512, b3, nullptr, U3[q],
                  w_acc + (size_t)(i + 1) * B_ROWS, 0, W4,
                  nullptr, nullptr, nullptr, nullptr};
      paired_kernel<1, 4><<<1024, 256, 0, stream>>>(bw3, f0, 512);
      paired_kernel<1, 0><<<1024, 256, 0, stream>>>(bw2, f1, 512);
      paired_kernel<1, 0><<<1024, 256, 0, stream>>>(bw1, f2, 512);
      paired_kernel<2, 3><<<640,  256, 0, stream>>>(gr0, f3, 128);
    } else {
      solo_kernel<1><<<512, 256, 0, stream>>>(bw3);
      solo_kernel<1><<<512, 256, 0, stream>>>(bw2);
      solo_kernel<1><<<512, 256, 0, stream>>>(bw1);
      solo_kernel<2><<<128, 256, 0, stream>>>(gr0);
    }
  }

  (void)in_sizes; (void)n_in; (void)out_size; (void)ws_size;
}